// Round 1
// baseline (941.725 us; speedup 1.0000x reference)
//
#include <hip/hip_runtime.h>
#include <hip/hip_bf16.h>
#include <stdint.h>

typedef float  floatx4 __attribute__((ext_vector_type(4)));
typedef short  short8  __attribute__((ext_vector_type(8)));
typedef unsigned short u16;

#define DIM 512
#define NH 16
#define HD 32
#define WS 49           // window size (tokens)
#define NBW 2048        // number of windows
#define NWIN 4          // mask groups
#define M_TOTAL (NBW*WS)    // 100352
#define N_QKV (3*DIM)       // 1536

// ---------- helpers ----------
__device__ __forceinline__ u16 f2bf(float f) {
    uint32_t u = __float_as_uint(f);
    u += 0x7FFFu + ((u >> 16) & 1u);   // RNE
    return (u16)(u >> 16);
}

__device__ __forceinline__ void load_lds16(const u16* g, u16* l) {
    __builtin_amdgcn_global_load_lds(
        (const __attribute__((address_space(1))) unsigned int*)g,
        (__attribute__((address_space(3))) unsigned int*)l, 16, 0, 0);
}

// ---------- cast x fp32 -> bf16 (vectorized) ----------
__global__ void cast_x_kernel(const float* __restrict__ in, u16* __restrict__ out, int n4) {
    int i = blockIdx.x * blockDim.x + threadIdx.x;
    if (i >= n4) return;
    const float4 v = ((const float4*)in)[i];
    ushort4 o;
    o.x = f2bf(v.x); o.y = f2bf(v.y); o.z = f2bf(v.z); o.w = f2bf(v.w);
    ((ushort4*)out)[i] = o;
}

// ---------- transpose + cast weight [K=512][N] -> Bt [N][512] bf16 ----------
__global__ void transpose_cast_kernel(const float* __restrict__ in, u16* __restrict__ out,
                                      int N, int total) {
    int idx = blockIdx.x * blockDim.x + threadIdx.x;   // idx = n*512 + k
    if (idx >= total) return;
    int k = idx & (DIM - 1);
    int n = idx >> 9;
    out[idx] = f2bf(in[k * N + n]);
}

// ---------- padded bias+mask table: comb[g][h][64][64] ----------
__global__ void build_comb_kernel(const float* __restrict__ bias_table, const int* __restrict__ rel_idx,
                                  const float* __restrict__ mask, float* __restrict__ comb) {
    int idx = blockIdx.x * blockDim.x + threadIdx.x;
    if (idx >= NWIN * NH * 64 * 64) return;
    int j = idx & 63, i = (idx >> 6) & 63, h = (idx >> 12) & 15, g = idx >> 16;
    float v = -1e30f;
    if (i < WS && j < WS)
        v = bias_table[rel_idx[i * WS + j] * NH + h] + mask[(g * WS + i) * WS + j];
    comb[idx] = v;
}

// ---------- 128x128 MFMA GEMM, C = A[M][K] * Bt[N][K]^T + bias ----------
template<bool OUT_BF16>
__global__ __launch_bounds__(256, 2) void gemm_bt_kernel(
    const u16* __restrict__ A, const u16* __restrict__ Bt,
    const float* __restrict__ bias, void* __restrict__ out, int N, int K)
{
    __shared__ __align__(16) u16 sA[128 * 32];
    __shared__ __align__(16) u16 sB[128 * 32];
    const int tid  = threadIdx.x;
    const int lane = tid & 63;
    const int wave = tid >> 6;
    const long m0 = (long)blockIdx.y * 128;
    const long n0 = (long)blockIdx.x * 128;
    const int rr = lane & 15;
    const int qk = (lane >> 4) * 8;
    const int wm = (wave >> 1) * 64;
    const int wn = (wave & 1) * 64;

    floatx4 acc[4][4];
    const floatx4 z4 = {0.f, 0.f, 0.f, 0.f};
#pragma unroll
    for (int mi = 0; mi < 4; ++mi)
#pragma unroll
        for (int ni = 0; ni < 4; ++ni) acc[mi][ni] = z4;

    // staging addresses: chunk c = tid (rows 0..63) and tid+256 (rows 64..127)
    const int row0 = tid >> 2;
    const int kc0  = (tid & 3) * 8;
    const u16* gA0 = A  + (m0 + row0) * K + kc0;
    const u16* gA1 = A  + (m0 + row0 + 64) * K + kc0;
    const u16* gB0 = Bt + (n0 + row0) * K + kc0;
    const u16* gB1 = Bt + (n0 + row0 + 64) * K + kc0;
    u16* lA0 = sA + tid * 8;
    u16* lA1 = sA + (tid + 256) * 8;
    u16* lB0 = sB + tid * 8;
    u16* lB1 = sB + (tid + 256) * 8;

    for (int k0 = 0; k0 < K; k0 += 32) {
        load_lds16(gA0 + k0, lA0);
        load_lds16(gA1 + k0, lA1);
        load_lds16(gB0 + k0, lB0);
        load_lds16(gB1 + k0, lB1);
        __syncthreads();
        short8 af[4], bfr[4];
#pragma unroll
        for (int mi = 0; mi < 4; ++mi)
            af[mi] = *(const short8*)(sA + (wm + mi * 16 + rr) * 32 + qk);
#pragma unroll
        for (int ni = 0; ni < 4; ++ni)
            bfr[ni] = *(const short8*)(sB + (wn + ni * 16 + rr) * 32 + qk);
#pragma unroll
        for (int mi = 0; mi < 4; ++mi)
#pragma unroll
            for (int ni = 0; ni < 4; ++ni)
                acc[mi][ni] = __builtin_amdgcn_mfma_f32_16x16x32_bf16(af[mi], bfr[ni], acc[mi][ni], 0, 0, 0);
        __syncthreads();
    }

    // epilogue: D[row=(lane>>4)*4+r][col=lane&15]
#pragma unroll
    for (int mi = 0; mi < 4; ++mi) {
#pragma unroll
        for (int r = 0; r < 4; ++r) {
            const long m = m0 + wm + mi * 16 + (lane >> 4) * 4 + r;
#pragma unroll
            for (int ni = 0; ni < 4; ++ni) {
                const long n = n0 + wn + ni * 16 + rr;
                float v = acc[mi][ni][r] + bias[n];
                if (OUT_BF16) ((u16*)out)[m * N + n] = f2bf(v);
                else          ((float*)out)[m * N + n] = v;
            }
        }
    }
}

// ---------- attention: one wave per (window, head) ----------
__global__ __launch_bounds__(64) void attn_kernel(
    const u16* __restrict__ qkv, const float* __restrict__ comb,
    u16* __restrict__ attn_out)
{
    const int bh = blockIdx.x;
    const int b = bh >> 4, h = bh & 15;
    const int l = threadIdx.x;
    const int rr = l & 15;
    const int qk = (l >> 4) * 8;

    __shared__ __align__(16) u16 qk_s[2 * 64 * 32];   // q rows 0..63 then k rows 0..63; reused as P[64][64]
    __shared__ __align__(16) u16 vT_s[32 * 64];
    __shared__ float rsum[64];
    u16* q_s = qk_s;
    u16* k_s = qk_s + 64 * 32;
    u16* p_s = qk_s;                                  // aliases q|k after fragments are in regs

    const u16* qg = qkv + (long)b * WS * N_QKV + h * HD;
    const u16* kg = qg + DIM;
    const u16* vg = qg + 2 * DIM;

    // zero vT (pad cols 49..63)
    for (int i = l; i < 32 * 64 / 2; i += 64) ((unsigned int*)vT_s)[i] = 0u;
    __syncthreads();
    // q/k rows (16B chunks), zero-pad rows 49..63
    for (int c = l; c < 256; c += 64) {
        const int row = c >> 2, kc8 = (c & 3) * 8;
        uint4 zq = {0, 0, 0, 0}, zk = {0, 0, 0, 0};
        if (row < WS) {
            zq = *(const uint4*)(qg + (long)row * N_QKV + kc8);
            zk = *(const uint4*)(kg + (long)row * N_QKV + kc8);
        }
        *(uint4*)(q_s + c * 8) = zq;
        *(uint4*)(k_s + c * 8) = zk;
    }
    // v transposed: vT[d][s]
    for (int t = l; t < WS * HD; t += 64) {
        const int row = t >> 5, d = t & 31;
        vT_s[d * 64 + row] = vg[(long)row * N_QKV + d];
    }
    __syncthreads();

    // fragments into registers
    short8 af[4], bfr[4];
#pragma unroll
    for (int mi = 0; mi < 4; ++mi) af[mi] = *(const short8*)(q_s + (mi * 16 + rr) * 32 + qk);
#pragma unroll
    for (int ni = 0; ni < 4; ++ni) bfr[ni] = *(const short8*)(k_s + (ni * 16 + rr) * 32 + qk);
    __syncthreads();   // all frags read before p_s overwrites q/k LDS

    floatx4 sc[4][4];
    const floatx4 z4 = {0.f, 0.f, 0.f, 0.f};
#pragma unroll
    for (int mi = 0; mi < 4; ++mi)
#pragma unroll
        for (int ni = 0; ni < 4; ++ni)
            sc[mi][ni] = __builtin_amdgcn_mfma_f32_16x16x32_bf16(af[mi], bfr[ni], z4, 0, 0, 0);

    // scale + bias + mask + softmax (unnormalized exp -> p_s, rowsum -> rsum)
    const float* cb = comb + (long)((b & (NWIN - 1)) * NH + h) * 4096;
    const float scale = 0.17677669529663689f;   // 32^-0.5
#pragma unroll
    for (int mi = 0; mi < 4; ++mi) {
#pragma unroll
        for (int r = 0; r < 4; ++r) {
            const int i = mi * 16 + (l >> 4) * 4 + r;
            float s0 = sc[mi][0][r] * scale + cb[i * 64 +  0 + rr];
            float s1 = sc[mi][1][r] * scale + cb[i * 64 + 16 + rr];
            float s2 = sc[mi][2][r] * scale + cb[i * 64 + 32 + rr];
            float s3 = sc[mi][3][r] * scale + cb[i * 64 + 48 + rr];
            float mx = fmaxf(fmaxf(s0, s1), fmaxf(s2, s3));
#pragma unroll
            for (int off = 1; off < 16; off <<= 1) mx = fmaxf(mx, __shfl_xor(mx, off, 64));
            float e0 = __expf(s0 - mx), e1 = __expf(s1 - mx);
            float e2 = __expf(s2 - mx), e3 = __expf(s3 - mx);
            float sm = e0 + e1 + e2 + e3;
#pragma unroll
            for (int off = 1; off < 16; off <<= 1) sm += __shfl_xor(sm, off, 64);
            p_s[i * 64 +  0 + rr] = f2bf(e0);
            p_s[i * 64 + 16 + rr] = f2bf(e1);
            p_s[i * 64 + 32 + rr] = f2bf(e2);
            p_s[i * 64 + 48 + rr] = f2bf(e3);
            if (rr == 0) rsum[i] = sm;
        }
    }
    __syncthreads();

    // PV: out[64][32] = P[64][64] @ V[64][32]
    floatx4 oacc[4][2];
#pragma unroll
    for (int mi = 0; mi < 4; ++mi) { oacc[mi][0] = z4; oacc[mi][1] = z4; }
#pragma unroll
    for (int kk = 0; kk < 2; ++kk) {
        short8 pf[4], vf[2];
#pragma unroll
        for (int mi = 0; mi < 4; ++mi)
            pf[mi] = *(const short8*)(p_s + (mi * 16 + rr) * 64 + kk * 32 + qk);
#pragma unroll
        for (int ni = 0; ni < 2; ++ni)
            vf[ni] = *(const short8*)(vT_s + (ni * 16 + rr) * 64 + kk * 32 + qk);
#pragma unroll
        for (int mi = 0; mi < 4; ++mi)
#pragma unroll
            for (int ni = 0; ni < 2; ++ni)
                oacc[mi][ni] = __builtin_amdgcn_mfma_f32_16x16x32_bf16(pf[mi], vf[ni], oacc[mi][ni], 0, 0, 0);
    }

    // epilogue: divide by rowsum, write attn_out[b][s][h*32+d] bf16
#pragma unroll
    for (int mi = 0; mi < 4; ++mi) {
#pragma unroll
        for (int r = 0; r < 4; ++r) {
            const int i = mi * 16 + (l >> 4) * 4 + r;
            if (i < WS) {
                const float inv = 1.0f / rsum[i];
                u16* op = attn_out + ((long)(b * WS + i)) * DIM + h * HD;
                op[rr]      = f2bf(oacc[mi][0][r] * inv);
                op[16 + rr] = f2bf(oacc[mi][1][r] * inv);
            }
        }
    }
}

// ---------- launch ----------
extern "C" void kernel_launch(void* const* d_in, const int* in_sizes, int n_in,
                              void* d_out, int out_size, void* d_ws, size_t ws_size,
                              hipStream_t stream)
{
    const float* x          = (const float*)d_in[0];
    const float* mask       = (const float*)d_in[1];
    const float* w_qkv      = (const float*)d_in[2];
    const float* b_qkv      = (const float*)d_in[3];
    const float* w_proj     = (const float*)d_in[4];
    const float* b_proj     = (const float*)d_in[5];
    const float* bias_table = (const float*)d_in[6];
    const int*   rel_idx    = (const int*)d_in[7];
    float* out = (float*)d_out;

    char* ws = (char*)d_ws;
    u16* x_bf   = (u16*)ws;  ws += (size_t)M_TOTAL * DIM * 2;        // 102.8 MB (reused as attn_out)
    u16* wqkvT  = (u16*)ws;  ws += (size_t)N_QKV * DIM * 2;          // 1.5 MB
    u16* wprojT = (u16*)ws;  ws += (size_t)DIM * DIM * 2;            // 0.5 MB
    float* comb = (float*)ws; ws += (size_t)NWIN * NH * 64 * 64 * 4; // 1.0 MB
    u16* qkv    = (u16*)ws;  ws += (size_t)M_TOTAL * N_QKV * 2;      // 308.3 MB
    u16* attn_o = x_bf;   // alias: x_bf dead after GEMM1

    const int n4 = M_TOTAL * DIM / 4;
    cast_x_kernel<<<(n4 + 255) / 256, 256, 0, stream>>>(x, x_bf, n4);
    transpose_cast_kernel<<<(N_QKV * DIM + 255) / 256, 256, 0, stream>>>(w_qkv, wqkvT, N_QKV, N_QKV * DIM);
    transpose_cast_kernel<<<(DIM * DIM + 255) / 256, 256, 0, stream>>>(w_proj, wprojT, DIM, DIM * DIM);
    build_comb_kernel<<<(NWIN * NH * 64 * 64 + 255) / 256, 256, 0, stream>>>(bias_table, rel_idx, mask, comb);

    gemm_bt_kernel<true><<<dim3(N_QKV / 128, M_TOTAL / 128), 256, 0, stream>>>(
        x_bf, wqkvT, b_qkv, qkv, N_QKV, DIM);

    attn_kernel<<<NBW * NH, 64, 0, stream>>>(qkv, comb, attn_o);

    gemm_bt_kernel<false><<<dim3(DIM / 128, M_TOTAL / 128), 256, 0, stream>>>(
        attn_o, wprojT, b_proj, out, DIM, DIM);
}

// Round 2
// 905.673 us; speedup vs baseline: 1.0398x; 1.0398x over previous
//
#include <hip/hip_runtime.h>
#include <hip/hip_bf16.h>
#include <stdint.h>

typedef float  floatx4 __attribute__((ext_vector_type(4)));
typedef short  short8  __attribute__((ext_vector_type(8)));
typedef unsigned short u16;

#define DIM 512
#define NH 16
#define HD 32
#define WS 49           // window size (tokens)
#define NBW 2048        // number of windows
#define NWIN 4          // mask groups
#define M_TOTAL (NBW*WS)    // 100352
#define N_QKV (3*DIM)       // 1536

// ---------- helpers ----------
__device__ __forceinline__ u16 f2bf(float f) {
    uint32_t u = __float_as_uint(f);
    u += 0x7FFFu + ((u >> 16) & 1u);   // RNE
    return (u16)(u >> 16);
}

__device__ __forceinline__ void load_lds16(const u16* g, u16* l) {
    __builtin_amdgcn_global_load_lds(
        (const __attribute__((address_space(1))) unsigned int*)g,
        (__attribute__((address_space(3))) unsigned int*)l, 16, 0, 0);
}

// ---------- cast x fp32 -> bf16 (vectorized) ----------
__global__ void cast_x_kernel(const float* __restrict__ in, u16* __restrict__ out, int n4) {
    int i = blockIdx.x * blockDim.x + threadIdx.x;
    if (i >= n4) return;
    const float4 v = ((const float4*)in)[i];
    ushort4 o;
    o.x = f2bf(v.x); o.y = f2bf(v.y); o.z = f2bf(v.z); o.w = f2bf(v.w);
    ((ushort4*)out)[i] = o;
}

// ---------- transpose + cast weight [K=512][N] -> Bt [N][512] bf16 ----------
__global__ void transpose_cast_kernel(const float* __restrict__ in, u16* __restrict__ out,
                                      int N, int total) {
    int idx = blockIdx.x * blockDim.x + threadIdx.x;   // idx = n*512 + k
    if (idx >= total) return;
    int k = idx & (DIM - 1);
    int n = idx >> 9;
    out[idx] = f2bf(in[k * N + n]);
}

// ---------- padded bias+mask table: comb[g][h][64][64] ----------
__global__ void build_comb_kernel(const float* __restrict__ bias_table, const int* __restrict__ rel_idx,
                                  const float* __restrict__ mask, float* __restrict__ comb) {
    int idx = blockIdx.x * blockDim.x + threadIdx.x;
    if (idx >= NWIN * NH * 64 * 64) return;
    int j = idx & 63, i = (idx >> 6) & 63, h = (idx >> 12) & 15, g = idx >> 16;
    float v = -1e30f;
    if (i < WS && j < WS)
        v = bias_table[rel_idx[i * WS + j] * NH + h] + mask[(g * WS + i) * WS + j];
    comb[idx] = v;
}

// ---------- 128x128 MFMA GEMM, C = A[M][K] * Bt[N][K]^T + bias ----------
template<bool OUT_BF16>
__global__ __launch_bounds__(256, 2) void gemm_bt_kernel(
    const u16* __restrict__ A, const u16* __restrict__ Bt,
    const float* __restrict__ bias, void* __restrict__ out, int N, int K)
{
    __shared__ __align__(16) u16 sA[128 * 32];
    __shared__ __align__(16) u16 sB[128 * 32];
    const int tid  = threadIdx.x;
    const int lane = tid & 63;
    const int wave = tid >> 6;
    const long m0 = (long)blockIdx.y * 128;
    const long n0 = (long)blockIdx.x * 128;
    const int rr = lane & 15;
    const int qk = (lane >> 4) * 8;
    const int wm = (wave >> 1) * 64;
    const int wn = (wave & 1) * 64;

    floatx4 acc[4][4];
    const floatx4 z4 = {0.f, 0.f, 0.f, 0.f};
#pragma unroll
    for (int mi = 0; mi < 4; ++mi)
#pragma unroll
        for (int ni = 0; ni < 4; ++ni) acc[mi][ni] = z4;

    // staging addresses: chunk c = tid (rows 0..63) and tid+256 (rows 64..127)
    const int row0 = tid >> 2;
    const int kc0  = (tid & 3) * 8;
    const u16* gA0 = A  + (m0 + row0) * K + kc0;
    const u16* gA1 = A  + (m0 + row0 + 64) * K + kc0;
    const u16* gB0 = Bt + (n0 + row0) * K + kc0;
    const u16* gB1 = Bt + (n0 + row0 + 64) * K + kc0;
    u16* lA0 = sA + tid * 8;
    u16* lA1 = sA + (tid + 256) * 8;
    u16* lB0 = sB + tid * 8;
    u16* lB1 = sB + (tid + 256) * 8;

    for (int k0 = 0; k0 < K; k0 += 32) {
        load_lds16(gA0 + k0, lA0);
        load_lds16(gA1 + k0, lA1);
        load_lds16(gB0 + k0, lB0);
        load_lds16(gB1 + k0, lB1);
        __syncthreads();
        short8 af[4], bfr[4];
#pragma unroll
        for (int mi = 0; mi < 4; ++mi)
            af[mi] = *(const short8*)(sA + (wm + mi * 16 + rr) * 32 + qk);
#pragma unroll
        for (int ni = 0; ni < 4; ++ni)
            bfr[ni] = *(const short8*)(sB + (wn + ni * 16 + rr) * 32 + qk);
#pragma unroll
        for (int mi = 0; mi < 4; ++mi)
#pragma unroll
            for (int ni = 0; ni < 4; ++ni)
                acc[mi][ni] = __builtin_amdgcn_mfma_f32_16x16x32_bf16(af[mi], bfr[ni], acc[mi][ni], 0, 0, 0);
        __syncthreads();
    }

    // epilogue: D[row=(lane>>4)*4+r][col=lane&15]
#pragma unroll
    for (int mi = 0; mi < 4; ++mi) {
#pragma unroll
        for (int r = 0; r < 4; ++r) {
            const long m = m0 + wm + mi * 16 + (lane >> 4) * 4 + r;
#pragma unroll
            for (int ni = 0; ni < 4; ++ni) {
                const long n = n0 + wn + ni * 16 + rr;
                float v = acc[mi][ni][r] + bias[n];
                if (OUT_BF16) ((u16*)out)[m * N + n] = f2bf(v);
                else          ((float*)out)[m * N + n] = v;
            }
        }
    }
}

// ---------- attention: one wave per (window, head); only P goes through LDS ----------
// P LDS layout: row i (64 rows), 8 blocks of 8 u16; logical block bb stored at
// position bb ^ (i & 7)  -> conflict-free b128 reads, 4-way writes.
__global__ __launch_bounds__(64, 4) void attn_kernel(
    const u16* __restrict__ qkv, const float* __restrict__ comb,
    u16* __restrict__ attn_out)
{
    const int bh = blockIdx.x;
    const int b = bh >> 4, h = bh & 15;
    const int l = threadIdx.x;
    const int rr = l & 15;
    const int q4 = l >> 4;
    const int qk = q4 * 8;

    __shared__ __align__(16) u16 p_s[64 * 64];

    const u16* qg = qkv + (long)b * WS * N_QKV + h * HD;
    const u16* kg = qg + DIM;
    const u16* vg = qg + 2 * DIM;

    // q (A-frag) and k (B-frag) loaded directly from global, zero for pad rows
    short8 af[4], bfr[4];
    const short8 z8 = {0, 0, 0, 0, 0, 0, 0, 0};
#pragma unroll
    for (int mi = 0; mi < 4; ++mi) {
        const int row = mi * 16 + rr;
        af[mi] = (row < WS) ? *(const short8*)(qg + (long)row * N_QKV + qk) : z8;
    }
#pragma unroll
    for (int ni = 0; ni < 4; ++ni) {
        const int row = ni * 16 + rr;
        bfr[ni] = (row < WS) ? *(const short8*)(kg + (long)row * N_QKV + qk) : z8;
    }

    // scores
    floatx4 sc[4][4];
    const floatx4 z4 = {0.f, 0.f, 0.f, 0.f};
#pragma unroll
    for (int mi = 0; mi < 4; ++mi)
#pragma unroll
        for (int ni = 0; ni < 4; ++ni)
            sc[mi][ni] = __builtin_amdgcn_mfma_f32_16x16x32_bf16(af[mi], bfr[ni], z4, 0, 0, 0);

    // V^T B-fragments directly from global (issued here so latency overlaps softmax VALU)
    short8 vf[2][2];
#pragma unroll
    for (int kk = 0; kk < 2; ++kk)
#pragma unroll
        for (int ni = 0; ni < 2; ++ni) {
            short8 t = z8;
            const int d = ni * 16 + rr;
#pragma unroll
            for (int j = 0; j < 8; ++j) {
                const int s = kk * 32 + qk + j;
                if (s < WS) t[j] = (short)vg[(long)s * N_QKV + d];
            }
            vf[kk][ni] = t;
        }

    // scale + bias + mask + softmax; unnormalized exp -> p_s (swizzled), rowsum in regs
    const float* cb = comb + (long)((b & (NWIN - 1)) * NH + h) * 4096;
    const float scale = 0.17677669529663689f;   // 32^-0.5
    float inv_s[4][4];
#pragma unroll
    for (int mi = 0; mi < 4; ++mi) {
#pragma unroll
        for (int r = 0; r < 4; ++r) {
            const int i = mi * 16 + q4 * 4 + r;
            float s0 = sc[mi][0][r] * scale + cb[i * 64 +  0 + rr];
            float s1 = sc[mi][1][r] * scale + cb[i * 64 + 16 + rr];
            float s2 = sc[mi][2][r] * scale + cb[i * 64 + 32 + rr];
            float s3 = sc[mi][3][r] * scale + cb[i * 64 + 48 + rr];
            float mx = fmaxf(fmaxf(s0, s1), fmaxf(s2, s3));
#pragma unroll
            for (int off = 1; off < 16; off <<= 1) mx = fmaxf(mx, __shfl_xor(mx, off, 64));
            float e0 = __expf(s0 - mx), e1 = __expf(s1 - mx);
            float e2 = __expf(s2 - mx), e3 = __expf(s3 - mx);
            float sm = e0 + e1 + e2 + e3;
#pragma unroll
            for (int off = 1; off < 16; off <<= 1) sm += __shfl_xor(sm, off, 64);
            inv_s[mi][r] = 1.0f / sm;
#pragma unroll
            for (int c = 0; c < 4; ++c) {
                const int col = c * 16 + rr;
                const int blk = (col >> 3) ^ (i & 7);
                const float ev = (c == 0) ? e0 : (c == 1) ? e1 : (c == 2) ? e2 : e3;
                p_s[i * 64 + blk * 8 + (col & 7)] = f2bf(ev);
            }
        }
    }
    __syncthreads();

    // PV: O[64][32] = P[64][64] @ V[64][32]
    floatx4 oacc[4][2];
#pragma unroll
    for (int mi = 0; mi < 4; ++mi) { oacc[mi][0] = z4; oacc[mi][1] = z4; }
#pragma unroll
    for (int kk = 0; kk < 2; ++kk) {
        short8 pf[4];
#pragma unroll
        for (int mi = 0; mi < 4; ++mi) {
            const int i2 = mi * 16 + rr;
            pf[mi] = *(const short8*)(p_s + i2 * 64 + (((4 * kk + q4) ^ (i2 & 7)) * 8));
        }
#pragma unroll
        for (int mi = 0; mi < 4; ++mi)
#pragma unroll
            for (int ni = 0; ni < 2; ++ni)
                oacc[mi][ni] = __builtin_amdgcn_mfma_f32_16x16x32_bf16(pf[mi], vf[kk][ni], oacc[mi][ni], 0, 0, 0);
    }

    // epilogue: divide by rowsum, write attn_out[b][s][h*32+d] bf16
#pragma unroll
    for (int mi = 0; mi < 4; ++mi) {
#pragma unroll
        for (int r = 0; r < 4; ++r) {
            const int i = mi * 16 + q4 * 4 + r;
            if (i < WS) {
                const float inv = inv_s[mi][r];
                u16* op = attn_out + ((long)(b * WS + i)) * DIM + h * HD;
                op[rr]      = f2bf(oacc[mi][0][r] * inv);
                op[16 + rr] = f2bf(oacc[mi][1][r] * inv);
            }
        }
    }
}

// ---------- launch ----------
extern "C" void kernel_launch(void* const* d_in, const int* in_sizes, int n_in,
                              void* d_out, int out_size, void* d_ws, size_t ws_size,
                              hipStream_t stream)
{
    const float* x          = (const float*)d_in[0];
    const float* mask       = (const float*)d_in[1];
    const float* w_qkv      = (const float*)d_in[2];
    const float* b_qkv      = (const float*)d_in[3];
    const float* w_proj     = (const float*)d_in[4];
    const float* b_proj     = (const float*)d_in[5];
    const float* bias_table = (const float*)d_in[6];
    const int*   rel_idx    = (const int*)d_in[7];
    float* out = (float*)d_out;

    char* ws = (char*)d_ws;
    u16* x_bf   = (u16*)ws;  ws += (size_t)M_TOTAL * DIM * 2;        // 102.8 MB (reused as attn_out)
    u16* wqkvT  = (u16*)ws;  ws += (size_t)N_QKV * DIM * 2;          // 1.5 MB
    u16* wprojT = (u16*)ws;  ws += (size_t)DIM * DIM * 2;            // 0.5 MB
    float* comb = (float*)ws; ws += (size_t)NWIN * NH * 64 * 64 * 4; // 1.0 MB
    u16* qkv    = (u16*)ws;  ws += (size_t)M_TOTAL * N_QKV * 2;      // 308.3 MB
    u16* attn_o = x_bf;   // alias: x_bf dead after GEMM1

    const int n4 = M_TOTAL * DIM / 4;
    cast_x_kernel<<<(n4 + 255) / 256, 256, 0, stream>>>(x, x_bf, n4);
    transpose_cast_kernel<<<(N_QKV * DIM + 255) / 256, 256, 0, stream>>>(w_qkv, wqkvT, N_QKV, N_QKV * DIM);
    transpose_cast_kernel<<<(DIM * DIM + 255) / 256, 256, 0, stream>>>(w_proj, wprojT, DIM, DIM * DIM);
    build_comb_kernel<<<(NWIN * NH * 64 * 64 + 255) / 256, 256, 0, stream>>>(bias_table, rel_idx, mask, comb);

    gemm_bt_kernel<true><<<dim3(N_QKV / 128, M_TOTAL / 128), 256, 0, stream>>>(
        x_bf, wqkvT, b_qkv, qkv, N_QKV, DIM);

    attn_kernel<<<NBW * NH, 64, 0, stream>>>(qkv, comb, attn_o);

    gemm_bt_kernel<false><<<dim3(DIM / 128, M_TOTAL / 128), 256, 0, stream>>>(
        attn_o, wprojT, b_proj, out, DIM, DIM);
}

// Round 3
// 856.492 us; speedup vs baseline: 1.0995x; 1.0574x over previous
//
#include <hip/hip_runtime.h>
#include <hip/hip_bf16.h>
#include <stdint.h>

typedef float  floatx4 __attribute__((ext_vector_type(4)));
typedef short  short8  __attribute__((ext_vector_type(8)));
typedef unsigned short u16;

#define DIM 512
#define NH 16
#define HD 32
#define WS 49           // window size (tokens)
#define NBW 2048        // number of windows
#define NWIN 4          // mask groups
#define M_TOTAL (NBW*WS)    // 100352
#define N_QKV (3*DIM)       // 1536

// ---------- helpers ----------
__device__ __forceinline__ u16 f2bf(float f) {
    uint32_t u = __float_as_uint(f);
    u += 0x7FFFu + ((u >> 16) & 1u);   // RNE
    return (u16)(u >> 16);
}

__device__ __forceinline__ void load_lds16(const u16* g, u16* l) {
    __builtin_amdgcn_global_load_lds(
        (const __attribute__((address_space(1))) unsigned int*)g,
        (__attribute__((address_space(3))) unsigned int*)l, 16, 0, 0);
}

// ---------- cast x fp32 -> bf16 (vectorized) ----------
__global__ void cast_x_kernel(const float* __restrict__ in, u16* __restrict__ out, int n4) {
    int i = blockIdx.x * blockDim.x + threadIdx.x;
    if (i >= n4) return;
    const float4 v = ((const float4*)in)[i];
    ushort4 o;
    o.x = f2bf(v.x); o.y = f2bf(v.y); o.z = f2bf(v.z); o.w = f2bf(v.w);
    ((ushort4*)out)[i] = o;
}

// ---------- transpose + cast weight [K=512][N] -> Bt [N][512] bf16 ----------
__global__ void transpose_cast_kernel(const float* __restrict__ in, u16* __restrict__ out,
                                      int N, int total) {
    int idx = blockIdx.x * blockDim.x + threadIdx.x;   // idx = n*512 + k
    if (idx >= total) return;
    int k = idx & (DIM - 1);
    int n = idx >> 9;
    out[idx] = f2bf(in[k * N + n]);
}

// ---------- padded bias+mask table, permuted for float4 lane loads ----------
// comb[(((g*16+h)*64 + i)*16 + jj)*4 + c] = value(row i, col c*16+jj), pad = -1e30
__global__ void build_comb_kernel(const float* __restrict__ bias_table, const int* __restrict__ rel_idx,
                                  const float* __restrict__ mask, float* __restrict__ comb) {
    int idx = blockIdx.x * blockDim.x + threadIdx.x;
    if (idx >= NWIN * NH * 64 * 64) return;
    int c = idx & 3, jj = (idx >> 2) & 15, i = (idx >> 6) & 63, h = (idx >> 12) & 15, g = idx >> 16;
    int j = c * 16 + jj;
    float v = -1e30f;
    if (i < WS && j < WS)
        v = bias_table[rel_idx[i * WS + j] * NH + h] + mask[(g * WS + i) * WS + j];
    comb[idx] = v;
}

// ---------- 128x128 MFMA GEMM, C = A[M][K] * Bt[N][K]^T + bias ----------
template<bool OUT_BF16>
__global__ __launch_bounds__(256, 2) void gemm_bt_kernel(
    const u16* __restrict__ A, const u16* __restrict__ Bt,
    const float* __restrict__ bias, void* __restrict__ out, int N, int K)
{
    __shared__ __align__(16) u16 sA[128 * 32];
    __shared__ __align__(16) u16 sB[128 * 32];
    const int tid  = threadIdx.x;
    const int lane = tid & 63;
    const int wave = tid >> 6;
    const long m0 = (long)blockIdx.y * 128;
    const long n0 = (long)blockIdx.x * 128;
    const int rr = lane & 15;
    const int qk = (lane >> 4) * 8;
    const int wm = (wave >> 1) * 64;
    const int wn = (wave & 1) * 64;

    floatx4 acc[4][4];
    const floatx4 z4 = {0.f, 0.f, 0.f, 0.f};
#pragma unroll
    for (int mi = 0; mi < 4; ++mi)
#pragma unroll
        for (int ni = 0; ni < 4; ++ni) acc[mi][ni] = z4;

    const int row0 = tid >> 2;
    const int kc0  = (tid & 3) * 8;
    const u16* gA0 = A  + (m0 + row0) * K + kc0;
    const u16* gA1 = A  + (m0 + row0 + 64) * K + kc0;
    const u16* gB0 = Bt + (n0 + row0) * K + kc0;
    const u16* gB1 = Bt + (n0 + row0 + 64) * K + kc0;
    u16* lA0 = sA + tid * 8;
    u16* lA1 = sA + (tid + 256) * 8;
    u16* lB0 = sB + tid * 8;
    u16* lB1 = sB + (tid + 256) * 8;

    for (int k0 = 0; k0 < K; k0 += 32) {
        load_lds16(gA0 + k0, lA0);
        load_lds16(gA1 + k0, lA1);
        load_lds16(gB0 + k0, lB0);
        load_lds16(gB1 + k0, lB1);
        __syncthreads();
        short8 af[4], bfr[4];
#pragma unroll
        for (int mi = 0; mi < 4; ++mi)
            af[mi] = *(const short8*)(sA + (wm + mi * 16 + rr) * 32 + qk);
#pragma unroll
        for (int ni = 0; ni < 4; ++ni)
            bfr[ni] = *(const short8*)(sB + (wn + ni * 16 + rr) * 32 + qk);
#pragma unroll
        for (int mi = 0; mi < 4; ++mi)
#pragma unroll
            for (int ni = 0; ni < 4; ++ni)
                acc[mi][ni] = __builtin_amdgcn_mfma_f32_16x16x32_bf16(af[mi], bfr[ni], acc[mi][ni], 0, 0, 0);
        __syncthreads();
    }

#pragma unroll
    for (int mi = 0; mi < 4; ++mi) {
#pragma unroll
        for (int r = 0; r < 4; ++r) {
            const long m = m0 + wm + mi * 16 + (lane >> 4) * 4 + r;
#pragma unroll
            for (int ni = 0; ni < 4; ++ni) {
                const long n = n0 + wn + ni * 16 + rr;
                float v = acc[mi][ni][r] + bias[n];
                if (OUT_BF16) ((u16*)out)[m * N + n] = f2bf(v);
                else          ((float*)out)[m * N + n] = v;
            }
        }
    }
}

// ---------- attention v3: one wave per (window, head, 32-row half) ----------
// No shuffle reductions: max-free softmax; row-sum via all-ones V B-tile in the
// PV MFMA. No cross-wave barrier (per-wave LDS P buffer + lgkmcnt(0)).
__global__ __launch_bounds__(256, 4) void attn_kernel(
    const u16* __restrict__ qkv, const float* __restrict__ comb,
    u16* __restrict__ attn_out)
{
    const int w   = threadIdx.x >> 6;
    const int l   = threadIdx.x & 63;
    const int job = blockIdx.x * 4 + w;          // job = b*32 + h*2 + half
    const int b    = job >> 5;
    const int h    = (job >> 1) & 15;
    const int half = job & 1;
    const int row0 = half * 32;
    const int rr = l & 15;
    const int q4 = l >> 4;
    const int qk = q4 * 8;

    __shared__ __align__(16) u16 p_s[4][32 * 64];
    u16* ps = p_s[w];

    const u16* qg = qkv + (long)b * WS * N_QKV + h * HD;
    const u16* kg = qg + DIM;
    const u16* vg = qg + 2 * DIM;

    const short8 z8 = {0, 0, 0, 0, 0, 0, 0, 0};
    const floatx4 z4 = {0.f, 0.f, 0.f, 0.f};

    // q A-frags (32 rows), k B-frags (full 64 cols)
    short8 af[2], bfr[4];
#pragma unroll
    for (int mi = 0; mi < 2; ++mi) {
        const int row = row0 + mi * 16 + rr;
        af[mi] = (row < WS) ? *(const short8*)(qg + (long)row * N_QKV + qk) : z8;
    }
#pragma unroll
    for (int ni = 0; ni < 4; ++ni) {
        const int row = ni * 16 + rr;
        bfr[ni] = (row < WS) ? *(const short8*)(kg + (long)row * N_QKV + qk) : z8;
    }

    // V^T B-frags, columns interleaved: tile0 -> d=2*rr (even), tile1 -> d=2*rr+1 (odd)
    short8 vf[2][2];
#pragma unroll
    for (int kk = 0; kk < 2; ++kk)
#pragma unroll
        for (int ni = 0; ni < 2; ++ni) {
            short8 t = z8;
            const int d = 2 * rr + ni;
#pragma unroll
            for (int j = 0; j < 8; ++j) {
                const int s = kk * 32 + qk + j;
                if (s < WS) t[j] = (short)vg[(long)s * N_QKV + d];
            }
            vf[kk][ni] = t;
        }
    // all-ones B-tile for row sums (bf16 1.0 = 0x3F80)
    short8 vones;
#pragma unroll
    for (int j = 0; j < 8; ++j) vones[j] = (short)0x3F80;

    // QK^T scores
    floatx4 sc[2][4];
#pragma unroll
    for (int mi = 0; mi < 2; ++mi)
#pragma unroll
        for (int ni = 0; ni < 4; ++ni)
            sc[mi][ni] = __builtin_amdgcn_mfma_f32_16x16x32_bf16(af[mi], bfr[ni], z4, 0, 0, 0);

    // max-free softmax numerator -> p_s (XOR-swizzled 16B blocks)
    const float4* cb4 = (const float4*)comb + ((long)((b & (NWIN - 1)) * NH + h)) * 1024;
    const float scale = 0.17677669529663689f;   // 32^-0.5
#pragma unroll
    for (int mi = 0; mi < 2; ++mi) {
#pragma unroll
        for (int r = 0; r < 4; ++r) {
            const int il = mi * 16 + q4 * 4 + r;       // local row 0..31
            const float4 cb = cb4[(row0 + il) * 16 + rr];
            float e0 = __expf(sc[mi][0][r] * scale + cb.x);
            float e1 = __expf(sc[mi][1][r] * scale + cb.y);
            float e2 = __expf(sc[mi][2][r] * scale + cb.z);
            float e3 = __expf(sc[mi][3][r] * scale + cb.w);
#pragma unroll
            for (int c = 0; c < 4; ++c) {
                const int col = c * 16 + rr;
                const int blk = (col >> 3) ^ (il & 7);
                const float ev = (c == 0) ? e0 : (c == 1) ? e1 : (c == 2) ? e2 : e3;
                ps[il * 64 + blk * 8 + (col & 7)] = f2bf(ev);
            }
        }
    }
    // same-wave LDS ordering: drain writes before reads (no cross-wave dependence)
    asm volatile("s_waitcnt lgkmcnt(0)" ::: "memory");

    // PV + row-sum: O[32][32] = P[32][64] @ V'[64][32], sums in ni=2 tile
    floatx4 oacc[2][3];
#pragma unroll
    for (int mi = 0; mi < 2; ++mi) { oacc[mi][0] = z4; oacc[mi][1] = z4; oacc[mi][2] = z4; }
#pragma unroll
    for (int kk = 0; kk < 2; ++kk) {
        short8 pf[2];
#pragma unroll
        for (int mi = 0; mi < 2; ++mi) {
            const int i2 = mi * 16 + rr;
            pf[mi] = *(const short8*)(ps + i2 * 64 + (((4 * kk + q4) ^ (i2 & 7)) * 8));
        }
#pragma unroll
        for (int mi = 0; mi < 2; ++mi) {
            oacc[mi][0] = __builtin_amdgcn_mfma_f32_16x16x32_bf16(pf[mi], vf[kk][0], oacc[mi][0], 0, 0, 0);
            oacc[mi][1] = __builtin_amdgcn_mfma_f32_16x16x32_bf16(pf[mi], vf[kk][1], oacc[mi][1], 0, 0, 0);
            oacc[mi][2] = __builtin_amdgcn_mfma_f32_16x16x32_bf16(pf[mi], vones,     oacc[mi][2], 0, 0, 0);
        }
    }

    // epilogue: normalize, pack d=2rr,2rr+1 into one u32 store
#pragma unroll
    for (int mi = 0; mi < 2; ++mi) {
#pragma unroll
        for (int r = 0; r < 4; ++r) {
            const int ig = row0 + mi * 16 + q4 * 4 + r;
            if (ig < WS) {
                const float inv = 1.0f / oacc[mi][2][r];
                const uint32_t lo = f2bf(oacc[mi][0][r] * inv);
                const uint32_t hi = f2bf(oacc[mi][1][r] * inv);
                uint32_t* op = (uint32_t*)(attn_out + ((long)(b * WS + ig)) * DIM + h * HD);
                op[rr] = lo | (hi << 16);
            }
        }
    }
}

// ---------- launch ----------
extern "C" void kernel_launch(void* const* d_in, const int* in_sizes, int n_in,
                              void* d_out, int out_size, void* d_ws, size_t ws_size,
                              hipStream_t stream)
{
    const float* x          = (const float*)d_in[0];
    const float* mask       = (const float*)d_in[1];
    const float* w_qkv      = (const float*)d_in[2];
    const float* b_qkv      = (const float*)d_in[3];
    const float* w_proj     = (const float*)d_in[4];
    const float* b_proj     = (const float*)d_in[5];
    const float* bias_table = (const float*)d_in[6];
    const int*   rel_idx    = (const int*)d_in[7];
    float* out = (float*)d_out;

    char* ws = (char*)d_ws;
    u16* x_bf   = (u16*)ws;  ws += (size_t)M_TOTAL * DIM * 2;        // 102.8 MB (reused as attn_out)
    u16* wqkvT  = (u16*)ws;  ws += (size_t)N_QKV * DIM * 2;          // 1.5 MB
    u16* wprojT = (u16*)ws;  ws += (size_t)DIM * DIM * 2;            // 0.5 MB
    float* comb = (float*)ws; ws += (size_t)NWIN * NH * 64 * 64 * 4; // 1.0 MB
    u16* qkv    = (u16*)ws;  ws += (size_t)M_TOTAL * N_QKV * 2;      // 308.3 MB
    u16* attn_o = x_bf;   // alias: x_bf dead after GEMM1

    const int n4 = M_TOTAL * DIM / 4;
    cast_x_kernel<<<(n4 + 255) / 256, 256, 0, stream>>>(x, x_bf, n4);
    transpose_cast_kernel<<<(N_QKV * DIM + 255) / 256, 256, 0, stream>>>(w_qkv, wqkvT, N_QKV, N_QKV * DIM);
    transpose_cast_kernel<<<(DIM * DIM + 255) / 256, 256, 0, stream>>>(w_proj, wprojT, DIM, DIM * DIM);
    build_comb_kernel<<<(NWIN * NH * 64 * 64 + 255) / 256, 256, 0, stream>>>(bias_table, rel_idx, mask, comb);

    gemm_bt_kernel<true><<<dim3(N_QKV / 128, M_TOTAL / 128), 256, 0, stream>>>(
        x_bf, wqkvT, b_qkv, qkv, N_QKV, DIM);

    attn_kernel<<<NBW * NH * 2 / 4, 256, 0, stream>>>(qkv, comb, attn_o);

    gemm_bt_kernel<false><<<dim3(DIM / 128, M_TOTAL / 128), 256, 0, stream>>>(
        attn_o, wprojT, b_proj, out, DIM, DIM);
}